// Round 10
// baseline (401.385 us; speedup 1.0000x reference)
//
#include <hip/hip_runtime.h>
#include <math.h>

#define HW 784      // 28*28
#define TSTEPS 30

struct GaussW { float w[7]; };

// Exact-rounded f32 ops (never fused/contracted) to bitwise-match numpy f32.
__device__ __forceinline__ float fadd(float a, float b) { return __fadd_rn(a, b); }
__device__ __forceinline__ float fmul(float a, float b) { return __fmul_rn(a, b); }
__device__ __forceinline__ float fsub(float a, float b) { return __fsub_rn(a, b); }

#if defined(__has_builtin)
#  if __has_builtin(__builtin_amdgcn_ubfe)
#    define UBFE(x, o, w) __builtin_amdgcn_ubfe((unsigned)(x), (unsigned)(o), (unsigned)(w))
#  endif
#endif
#ifndef UBFE
#  define UBFE(x, o, w) (((unsigned)(x) >> (o)) & ((1u << (w)) - 1u))
#endif

// In-wave phase fence: waits all outstanding LDS ops (DS ops of one wave are
// processed in order; this is the write->read cross-lane guarantee) and acts
// as a compiler memory barrier.
#define WFENCE() asm volatile("s_waitcnt lgkmcnt(0)" ::: "memory")

__device__ __forceinline__ int refl(int i, int n) {
    if (i < 0) return -i - 1;
    if (i >= n) return 2 * n - 1 - i;
    return i;
}

// Block-wide DoG (fallback path only), bit-exact numpy-f32 order.
__device__ void dog_sample(const float* __restrict__ x, int b, int nbatch,
                           const GaussW gw, float* g, float* t,
                           float* dout, int tid) {
    for (int p = tid; p < HW; p += 256) {
        float acc = fmul(gw.w[0], x[(size_t)refl(b - 3, nbatch) * HW + p]);
        #pragma unroll
        for (int k = 1; k < 7; ++k)
            acc = fadd(acc, fmul(gw.w[k], x[(size_t)refl(b - 3 + k, nbatch) * HW + p]));
        float h = fmul(gw.w[0], acc);
        #pragma unroll
        for (int k = 1; k < 7; ++k)
            h = fadd(h, fmul(gw.w[k], acc));
        g[p] = h;
    }
    __syncthreads();
    for (int p = tid; p < HW; p += 256) {
        int i = p / 28, j = p - (p / 28) * 28;
        float acc = fmul(gw.w[0], g[refl(i - 3, 28) * 28 + j]);
        #pragma unroll
        for (int k = 1; k < 7; ++k)
            acc = fadd(acc, fmul(gw.w[k], g[refl(i - 3 + k, 28) * 28 + j]));
        t[p] = acc;
    }
    __syncthreads();
    for (int p = tid; p < HW; p += 256) {
        int i = p / 28, j = p - (p / 28) * 28;
        float acc = fmul(gw.w[0], t[i * 28 + refl(j - 3, 28)]);
        #pragma unroll
        for (int k = 1; k < 7; ++k)
            acc = fadd(acc, fmul(gw.w[k], t[i * 28 + refl(j - 3 + k, 28)]));
        dout[p] = fabsf(fsub(acc, x[(size_t)b * HW + p]));
    }
    __syncthreads();
}

__global__ void init_kernel(unsigned int* dmax) { *dmax = 0u; }

// Wave-per-sample DoG + global max (+ optional dcache write). No barriers.
template<bool CACHE>
__global__ __launch_bounds__(256) void dmax_kernel(const float* __restrict__ x,
                                                   int nbatch, GaussW gw,
                                                   unsigned int* __restrict__ dmax,
                                                   float* __restrict__ dcache) {
    __shared__ float gS[4][HW];
    __shared__ float tS[4][HW];
    int tid = threadIdx.x;
    int lane = tid & 63, wv = tid >> 6;
    int b = blockIdx.x * 4 + wv;
    int bs = b < nbatch ? b : nbatch - 1;
    float* g = gS[wv];
    float* t = tS[wv];
    const float* xb = x + (size_t)bs * HW;
    const float* xr[7];
    #pragma unroll
    for (int k = 0; k < 7; ++k)
        xr[k] = x + (size_t)refl(bs - 3 + k, nbatch) * HW;

    // stage 1: axis0 (batch) + axis1 -> g
    for (int r = 0; r < 13; ++r) {
        int p = (r << 6) + lane;
        if (p < HW) {
            float acc = fmul(gw.w[0], xr[0][p]);
            #pragma unroll
            for (int k = 1; k < 7; ++k)
                acc = fadd(acc, fmul(gw.w[k], xr[k][p]));
            float h = fmul(gw.w[0], acc);
            #pragma unroll
            for (int k = 1; k < 7; ++k)
                h = fadd(h, fmul(gw.w[k], acc));
            g[p] = h;
        }
    }
    WFENCE();
    // stage 2: axis2 (rows) -> t
    for (int r = 0; r < 13; ++r) {
        int p = (r << 6) + lane;
        if (p < HW) {
            int i = p / 28, j = p - (p / 28) * 28;
            float acc = fmul(gw.w[0], g[refl(i - 3, 28) * 28 + j]);
            #pragma unroll
            for (int k = 1; k < 7; ++k)
                acc = fadd(acc, fmul(gw.w[k], g[refl(i - 3 + k, 28) * 28 + j]));
            t[p] = acc;
        }
    }
    WFENCE();
    // stage 3: axis3 (cols), d = |blur - x|, cache + max
    float mx = 0.f;
    for (int r = 0; r < 13; ++r) {
        int p = (r << 6) + lane;
        if (p < HW) {
            int i = p / 28, j = p - (p / 28) * 28;
            float acc = fmul(gw.w[0], t[i * 28 + refl(j - 3, 28)]);
            #pragma unroll
            for (int k = 1; k < 7; ++k)
                acc = fadd(acc, fmul(gw.w[k], t[i * 28 + refl(j - 3 + k, 28)]));
            float d = fabsf(fsub(acc, xb[p]));
            if (CACHE) dcache[(size_t)bs * HW + p] = d;
            mx = fmaxf(mx, d);
        }
    }
    #pragma unroll
    for (int off = 32; off; off >>= 1) mx = fmaxf(mx, __shfl_down(mx, off, 64));
    if (lane == 0) atomicMax(dmax, __float_as_uint(mx));  // d>=0: bit-max ok
}

// Wave-per-sample simulation: 4 samples/block, zero block barriers in the loop.
template<bool CACHE>
__global__ __launch_bounds__(256, 3) void sim_kernel(const float* __restrict__ x,
        int nbatch,
        const float* __restrict__ w1g, const float* __restrict__ w2g,
        const float* __restrict__ w3g, GaussW gw,
        const unsigned int* __restrict__ dmaxp,
        const float* __restrict__ dcache,
        float* __restrict__ out) {
    __shared__ __align__(16) float4 lut[512];   // conv1 LUT (shared; DoG scratch pre-build)
    __shared__ __align__(8)  float2 lut2[768];  // conv2 row-pair LUT
    __shared__ float lut3[96];                  // conv3 row LUT
    __shared__ float wts[216];
    __shared__ __align__(16) float dnS[4][800]; // per-wave normalized DoG (pad to 800)
    __shared__ unsigned s1S[4][28];             // per-wave layer-1 spike rows
    __shared__ unsigned p1S[4][52];             // per-wave pooled-1 masks [4c][13r], bits<<1
    __shared__ unsigned p2S[4][24];             // per-wave pooled-2 masks [4c][6r]

    int tid = threadIdx.x;
    int lane = tid & 63, wv = tid >> 6;
    int b4 = blockIdx.x * 4;

    // ---------- block prologue (the only __syncthreads) ----------
    if (!CACHE) {
        float* scr = (float*)lut;   // 2048 floats >= 2*784
        for (int s = 0; s < 4; ++s) {
            int bb = b4 + s; if (bb >= nbatch) bb = nbatch - 1;
            dog_sample(x, bb, nbatch, gw, scr, scr + HW, &dnS[s][0], tid);
        }
    }
    if (tid < 36)  wts[tid]       = w1g[tid];
    if (tid < 144) wts[36 + tid]  = w2g[tid];
    if (tid < 36)  wts[180 + tid] = w3g[tid];
    __syncthreads();
    for (int e = tid; e < 512; e += 256) {
        float a0 = 0.f, a1 = 0.f, a2 = 0.f, a3 = 0.f;
        #pragma unroll
        for (int k = 0; k < 9; ++k) {
            bool bit = (e >> k) & 1;
            a0 = fadd(a0, bit ? wts[k]      : 0.0f);
            a1 = fadd(a1, bit ? wts[9 + k]  : 0.0f);
            a2 = fadd(a2, bit ? wts[18 + k] : 0.0f);
            a3 = fadd(a3, bit ? wts[27 + k] : 0.0f);
        }
        lut[e] = make_float4(a0, a1, a2, a3);
    }
    for (int e = tid; e < 768; e += 256) {
        int rowIdx = e >> 4, idx = e & 15;
        int cout = rowIdx / 12, rem = rowIdx - cout * 12;
        int ic = rem / 3, ki = rem - ic * 3;
        const float* wb = &wts[36 + cout * 36 + ic * 9 + ki * 3];
        float xx = 0.f, yy = 0.f;
        #pragma unroll
        for (int kk = 0; kk < 3; ++kk) {
            xx = fadd(xx, ((idx >> kk) & 1) ? wb[kk] : 0.0f);
            yy = fadd(yy, ((idx >> (kk + 1)) & 1) ? wb[kk] : 0.0f);
        }
        lut2[e] = make_float2(xx, yy);
    }
    if (tid < 96) {
        int ric = tid >> 3, idx = tid & 7;
        int ic = ric / 3, ki = ric - ic * 3;
        const float* wb = &wts[180 + ic * 9 + ki * 3];
        float xx = 0.f;
        #pragma unroll
        for (int kk = 0; kk < 3; ++kk)
            xx = fadd(xx, ((idx >> kk) & 1) ? wb[kk] : 0.0f);
        lut3[tid] = xx;
    }
    __syncthreads();

    // ---------- per-wave section: one sample, no block barriers ----------
    int b = b4 + wv;
    if (b >= nbatch) return;

    float* dn = dnS[wv];
    unsigned* s1 = s1S[wv];
    unsigned* p1 = p1S[wv];
    unsigned* p2 = p2S[wv];

    float dmaxv = __uint_as_float(*dmaxp);
    if (CACHE) {
        const float* dcb = dcache + (size_t)b * HW;
        for (int r = 0; r < 13; ++r) {
            int p = (r << 6) + lane;
            if (p < HW) dn[p] = __fdiv_rn(dcb[p], dmaxv);
        }
    } else {
        for (int r = 0; r < 13; ++r) {
            int p = (r << 6) + lane;
            if (p < HW) dn[p] = __fdiv_rn(dn[p], dmaxv);
        }
    }
    if (lane < 16) dn[HW + lane] = 0.f;           // pad [784,800)
    if (lane < 52) p1[lane] = 0u;
    if (lane < 24) p2[lane] = 0u;
    WFENCE();

    // ---- fixed per-lane geometry ----
    // conv1 quads: q = lane + 64k (k<3, q<169)
    int sr1[3], pi1[3]; unsigned sh1[3], pb1[3]; bool ok1[3];
    #pragma unroll
    for (int k = 0; k < 3; ++k) {
        int q = lane + (k << 6);
        ok1[k] = q < 169;
        if (q >= 169) q = 0;
        int pi = q / 13, pj = q - pi * 13;
        sr1[k] = 2 * pi; sh1[k] = (unsigned)(2 * pj);
        pi1[k] = pi; pb1[k] = 1u << (pj + 1);
    }
    // conv2 items: m = lane + 64k (k<5, m<264); item = (row, sub): row=(c,i2) of 44,
    // sub<5 -> col pair j0=2*sub, sub=5 -> single j0=10.
    int i2c[5], lb2[5], p2w2[5]; unsigned js2[5], b20[5], b21[5]; bool ok2[5];
    #pragma unroll
    for (int k = 0; k < 5; ++k) {
        int m = lane + (k << 6);
        ok2[k] = m < 264;
        if (m >= 264) m = 0;
        int row = m / 6, sub = m - row * 6;
        int j0 = (sub < 5) ? 2 * sub : 10;
        int c = row / 11, i2 = row - c * 11;
        i2c[k] = i2; js2[k] = (unsigned)(j0 + 1); lb2[k] = c * 192;
        p2w2[k] = c * 6 + ((i2 + 1) >> 1);
        b20[k] = 1u << (j0 >> 1);
        b21[k] = (sub < 5) ? (2u << (j0 >> 1)) : 0u;
    }
    int rr3 = (lane >> 2) & 3, cc3 = lane & 3;

    // ---- membranes (registers) ----
    float v2q[3][16] = {};
    float v3s[5][2] = {};
    float v1m[14] = {};
    float v4 = 0.f, pred = 0.f;

    #pragma unroll 1
    for (int t = 0; t < TSTEPS; ++t) {
        // ======== phase 1: layer1 (lanes<56, 14 row-pair rounds) | zero p2 ========
        #pragma unroll
        for (int r = 0; r < 14; ++r) {
            float dv = dn[r * 56 + lane];          // max idx 791 < 800 (pad=0)
            float v = fadd(v1m[r], dv);
            bool spk = (lane < 56) && (v >= 4.5f);
            v1m[r] = spk ? 0.f : v;
            unsigned long long bal = __ballot(spk);
            if (lane < 2)
                s1[2 * r + lane] = (unsigned)(lane ? (bal >> 28) : bal) & 0x0FFFFFFFu;
        }
        if (lane >= 56) {
            int w = lane - 56;
            p2[w] = 0u; p2[w + 8] = 0u; p2[w + 16] = 0u;
        }
        WFENCE();

        // ======== phase 2: conv1 (IF 4.5 + maxpool) ========
        #pragma unroll
        for (int k = 0; k < 3; ++k) {
            if (ok1[k]) {
                int sr = sr1[k];
                unsigned m0 = s1[sr], m1 = s1[sr + 1], m2 = s1[sr + 2], m3 = s1[sr + 3];
                unsigned sh = sh1[k];
                unsigned a = UBFE(m0, sh, 4), bq = UBFE(m1, sh, 4),
                         cq = UBFE(m2, sh, 4), dq = UBFE(m3, sh, 4);
                unsigned a7 = a & 7u, b7 = bq & 7u, c7 = cq & 7u, d7 = dq & 7u;
                unsigned a1 = a >> 1, b1 = bq >> 1, c1 = cq >> 1, d1 = dq >> 1;
                unsigned p00 = a7 | (b7 << 3) | (c7 << 6);
                unsigned p01 = a1 | (b1 << 3) | (c1 << 6);
                unsigned p10 = b7 | (c7 << 3) | (d7 << 6);
                unsigned p11 = b1 | (c1 << 3) | (d1 << 6);
                float4 e00 = lut[p00], e01 = lut[p01], e10 = lut[p10], e11 = lut[p11];
                unsigned cb0 = 0, cb1 = 0, cb2 = 0, cb3 = 0;
                #define C1U(E, ci) { float v; bool s; \
                    v = fadd(v2q[k][(ci)*4+0], E.x); s = v>=4.5f; v2q[k][(ci)*4+0] = s?0.f:v; cb0 |= (unsigned)s; \
                    v = fadd(v2q[k][(ci)*4+1], E.y); s = v>=4.5f; v2q[k][(ci)*4+1] = s?0.f:v; cb1 |= (unsigned)s; \
                    v = fadd(v2q[k][(ci)*4+2], E.z); s = v>=4.5f; v2q[k][(ci)*4+2] = s?0.f:v; cb2 |= (unsigned)s; \
                    v = fadd(v2q[k][(ci)*4+3], E.w); s = v>=4.5f; v2q[k][(ci)*4+3] = s?0.f:v; cb3 |= (unsigned)s; }
                C1U(e00, 0) C1U(e01, 1) C1U(e10, 2) C1U(e11, 3)
                #undef C1U
                int pw = pi1[k]; unsigned bt = pb1[k];
                if (cb0) atomicOr(&p1[pw],      bt);
                if (cb1) atomicOr(&p1[13 + pw], bt);
                if (cb2) atomicOr(&p1[26 + pw], bt);
                if (cb3) atomicOr(&p1[39 + pw], bt);
            }
        }
        WFENCE();

        // ======== phase 3: conv2 (IF 1.0 + maxpool pad=1) ========
        #pragma unroll
        for (int k = 0; k < 5; ++k) {
            if (ok2[k]) {
                float accA = 0.f, accB = 0.f;
                #pragma unroll
                for (int ic = 0; ic < 4; ++ic)
                    #pragma unroll
                    for (int ki = 0; ki < 3; ++ki) {
                        unsigned row = p1[ic * 13 + i2c[k] + ki];
                        unsigned idx = UBFE(row, js2[k], 4);
                        float2 e = lut2[lb2[k] + (ic * 3 + ki) * 16 + idx];
                        accA = fadd(accA, e.x);
                        accB = fadd(accB, e.y);
                    }
                float va = fadd(v3s[k][0], accA);
                float vb = fadd(v3s[k][1], accB);
                bool sa = va >= 1.0f, sb = vb >= 1.0f;
                v3s[k][0] = sa ? 0.f : va;
                v3s[k][1] = sb ? 0.f : vb;
                unsigned orm = (sa ? b20[k] : 0u) | (sb ? b21[k] : 0u);
                if (orm) atomicOr(&p2[p2w2[k]], orm);
            }
        }
        WFENCE();

        // ======== phase 4: conv3 + LIF (lanes<16) | zero p1 (lanes>=16) ========
        if (lane < 16) {
            float acc = 0.f;
            #pragma unroll
            for (int ic = 0; ic < 4; ++ic)
                #pragma unroll
                for (int ki = 0; ki < 3; ++ki) {
                    unsigned row = p2[ic * 6 + rr3 + ki];
                    unsigned idx = UBFE(row, cc3, 3);
                    acc = fadd(acc, lut3[(ic * 3 + ki) * 8 + idx]);
                }
            v4 = fadd(v4, fmul(fsub(acc, v4), 0.5f));
            if (v4 >= 1.0f) { pred += 1.f; v4 = 0.f; }
        } else {
            int w = lane - 16;
            p1[w] = 0u;
            if (w < 4) p1[48 + w] = 0u;
        }
        WFENCE();
    }

    if (lane < 16) out[(size_t)b * 16 + lane] = __fdiv_rn(pred, 30.0f);
}

extern "C" void kernel_launch(void* const* d_in, const int* in_sizes, int n_in,
                              void* d_out, int out_size, void* d_ws, size_t ws_size,
                              hipStream_t stream) {
    const float* x  = (const float*)d_in[0];
    const float* w1 = (const float*)d_in[1];
    const float* w2 = (const float*)d_in[2];
    const float* w3 = (const float*)d_in[3];
    float* out = (float*)d_out;
    unsigned int* dmax = (unsigned int*)d_ws;
    float* dcache = (float*)((char*)d_ws + 16);

    int nbatch = in_sizes[0] / HW;
    size_t need = 16 + (size_t)nbatch * HW * sizeof(float);
    bool cache = ws_size >= need;
    int g4 = (nbatch + 3) / 4;

    // numpy-f32 Gaussian weights: exact f32 steps + correctly-rounded exp
    GaussW gw;
    {
        float fw[7];
        for (int k = 0; k < 7; ++k) {
            float iv = (float)(k - 3);
            float q = iv / 2.0f;
            float e = -0.5f * (q * q);
            fw[k] = (float)exp((double)e);
        }
        float s = 0.0f;
        for (int k = 0; k < 7; ++k) s += fw[k];
        for (int k = 0; k < 7; ++k) gw.w[k] = fw[k] / s;
    }

    hipLaunchKernelGGL(init_kernel, dim3(1), dim3(1), 0, stream, dmax);
    if (cache) {
        hipLaunchKernelGGL(dmax_kernel<true>, dim3(g4), dim3(256), 0, stream,
                           x, nbatch, gw, dmax, dcache);
        hipLaunchKernelGGL(sim_kernel<true>, dim3(g4), dim3(256), 0, stream,
                           x, nbatch, w1, w2, w3, gw, dmax, dcache, out);
    } else {
        hipLaunchKernelGGL(dmax_kernel<false>, dim3(g4), dim3(256), 0, stream,
                           x, nbatch, gw, dmax, dcache);
        hipLaunchKernelGGL(sim_kernel<false>, dim3(g4), dim3(256), 0, stream,
                           x, nbatch, w1, w2, w3, gw, dmax, dcache, out);
    }
}

// Round 11
// 398.540 us; speedup vs baseline: 1.0071x; 1.0071x over previous
//
#include <hip/hip_runtime.h>
#include <math.h>

#define HW 784      // 28*28
#define TSTEPS 30

struct GaussW { float w[7]; };

// Exact-rounded f32 ops (never fused/contracted) to bitwise-match numpy f32.
__device__ __forceinline__ float fadd(float a, float b) { return __fadd_rn(a, b); }
__device__ __forceinline__ float fmul(float a, float b) { return __fmul_rn(a, b); }
__device__ __forceinline__ float fsub(float a, float b) { return __fsub_rn(a, b); }

#if defined(__has_builtin)
#  if __has_builtin(__builtin_amdgcn_ubfe)
#    define UBFE(x, o, w) __builtin_amdgcn_ubfe((unsigned)(x), (unsigned)(o), (unsigned)(w))
#  endif
#endif
#ifndef UBFE
#  define UBFE(x, o, w) (((unsigned)(x) >> (o)) & ((1u << (w)) - 1u))
#endif

// In-wave phase fence: waits all outstanding LDS ops (DS ops of one wave are
// processed in order) and acts as a compiler memory barrier.
#define WFENCE() asm volatile("s_waitcnt lgkmcnt(0)" ::: "memory")

__device__ __forceinline__ int refl(int i, int n) {
    if (i < 0) return -i - 1;
    if (i >= n) return 2 * n - 1 - i;
    return i;
}

// Block-wide DoG (fallback path only), bit-exact numpy-f32 order.
__device__ void dog_sample(const float* __restrict__ x, int b, int nbatch,
                           const GaussW gw, float* g, float* t,
                           float* dout, int tid) {
    for (int p = tid; p < HW; p += 256) {
        float acc = fmul(gw.w[0], x[(size_t)refl(b - 3, nbatch) * HW + p]);
        #pragma unroll
        for (int k = 1; k < 7; ++k)
            acc = fadd(acc, fmul(gw.w[k], x[(size_t)refl(b - 3 + k, nbatch) * HW + p]));
        float h = fmul(gw.w[0], acc);
        #pragma unroll
        for (int k = 1; k < 7; ++k)
            h = fadd(h, fmul(gw.w[k], acc));
        g[p] = h;
    }
    __syncthreads();
    for (int p = tid; p < HW; p += 256) {
        int i = p / 28, j = p - (p / 28) * 28;
        float acc = fmul(gw.w[0], g[refl(i - 3, 28) * 28 + j]);
        #pragma unroll
        for (int k = 1; k < 7; ++k)
            acc = fadd(acc, fmul(gw.w[k], g[refl(i - 3 + k, 28) * 28 + j]));
        t[p] = acc;
    }
    __syncthreads();
    for (int p = tid; p < HW; p += 256) {
        int i = p / 28, j = p - (p / 28) * 28;
        float acc = fmul(gw.w[0], t[i * 28 + refl(j - 3, 28)]);
        #pragma unroll
        for (int k = 1; k < 7; ++k)
            acc = fadd(acc, fmul(gw.w[k], t[i * 28 + refl(j - 3 + k, 28)]));
        dout[p] = fabsf(fsub(acc, x[(size_t)b * HW + p]));
    }
    __syncthreads();
}

__global__ void init_kernel(unsigned int* dmax) { *dmax = 0u; }

// Wave-per-sample DoG + global max (+ optional dcache write). No barriers.
template<bool CACHE>
__global__ __launch_bounds__(256) void dmax_kernel(const float* __restrict__ x,
                                                   int nbatch, GaussW gw,
                                                   unsigned int* __restrict__ dmax,
                                                   float* __restrict__ dcache) {
    __shared__ float gS[4][HW];
    __shared__ float tS[4][HW];
    int tid = threadIdx.x;
    int lane = tid & 63, wv = tid >> 6;
    int b = blockIdx.x * 4 + wv;
    int bs = b < nbatch ? b : nbatch - 1;
    float* g = gS[wv];
    float* t = tS[wv];
    const float* xb = x + (size_t)bs * HW;
    const float* xr[7];
    #pragma unroll
    for (int k = 0; k < 7; ++k)
        xr[k] = x + (size_t)refl(bs - 3 + k, nbatch) * HW;

    for (int r = 0; r < 13; ++r) {
        int p = (r << 6) + lane;
        if (p < HW) {
            float acc = fmul(gw.w[0], xr[0][p]);
            #pragma unroll
            for (int k = 1; k < 7; ++k)
                acc = fadd(acc, fmul(gw.w[k], xr[k][p]));
            float h = fmul(gw.w[0], acc);
            #pragma unroll
            for (int k = 1; k < 7; ++k)
                h = fadd(h, fmul(gw.w[k], acc));
            g[p] = h;
        }
    }
    WFENCE();
    for (int r = 0; r < 13; ++r) {
        int p = (r << 6) + lane;
        if (p < HW) {
            int i = p / 28, j = p - (p / 28) * 28;
            float acc = fmul(gw.w[0], g[refl(i - 3, 28) * 28 + j]);
            #pragma unroll
            for (int k = 1; k < 7; ++k)
                acc = fadd(acc, fmul(gw.w[k], g[refl(i - 3 + k, 28) * 28 + j]));
            t[p] = acc;
        }
    }
    WFENCE();
    float mx = 0.f;
    for (int r = 0; r < 13; ++r) {
        int p = (r << 6) + lane;
        if (p < HW) {
            int i = p / 28, j = p - (p / 28) * 28;
            float acc = fmul(gw.w[0], t[i * 28 + refl(j - 3, 28)]);
            #pragma unroll
            for (int k = 1; k < 7; ++k)
                acc = fadd(acc, fmul(gw.w[k], t[i * 28 + refl(j - 3 + k, 28)]));
            float d = fabsf(fsub(acc, xb[p]));
            if (CACHE) dcache[(size_t)bs * HW + p] = d;
            mx = fmaxf(mx, d);
        }
    }
    #pragma unroll
    for (int off = 32; off; off >>= 1) mx = fmaxf(mx, __shfl_down(mx, off, 64));
    if (lane == 0) atomicMax(dmax, __float_as_uint(mx));  // d>=0: bit-max ok
}

// ---- per-phase building blocks (bit-exact, verified in r10) ----

__device__ __forceinline__ void layer1_step(const float* dn, unsigned* s1,
                                            float (&v1m)[14], int lane) {
    #pragma unroll
    for (int r = 0; r < 14; ++r) {
        float dv = dn[r * 56 + lane];          // max idx 791 < 800 (pad=0)
        float v = fadd(v1m[r], dv);
        bool spk = (lane < 56) && (v >= 4.5f);
        v1m[r] = spk ? 0.f : v;
        unsigned long long bal = __ballot(spk);
        if (lane < 2)
            s1[2 * r + lane] = (unsigned)(lane ? (bal >> 28) : bal) & 0x0FFFFFFFu;
    }
}

__device__ __forceinline__ void conv1_step(const unsigned* s1, unsigned* p1,
        float (&v2q)[3][16], const float4* lut,
        const int (&sr1)[3], const int (&pi1)[3], const unsigned (&sh1)[3],
        const unsigned (&pb1)[3], const bool (&ok1)[3]) {
    #pragma unroll
    for (int k = 0; k < 3; ++k) {
        if (ok1[k]) {
            int sr = sr1[k];
            unsigned m0 = s1[sr], m1 = s1[sr + 1], m2 = s1[sr + 2], m3 = s1[sr + 3];
            unsigned sh = sh1[k];
            unsigned a = UBFE(m0, sh, 4), bq = UBFE(m1, sh, 4),
                     cq = UBFE(m2, sh, 4), dq = UBFE(m3, sh, 4);
            unsigned a7 = a & 7u, b7 = bq & 7u, c7 = cq & 7u, d7 = dq & 7u;
            unsigned a1 = a >> 1, b1 = bq >> 1, c1 = cq >> 1, d1 = dq >> 1;
            unsigned p00 = a7 | (b7 << 3) | (c7 << 6);
            unsigned p01 = a1 | (b1 << 3) | (c1 << 6);
            unsigned p10 = b7 | (c7 << 3) | (d7 << 6);
            unsigned p11 = b1 | (c1 << 3) | (d1 << 6);
            float4 e00 = lut[p00], e01 = lut[p01], e10 = lut[p10], e11 = lut[p11];
            unsigned cb0 = 0, cb1 = 0, cb2 = 0, cb3 = 0;
            #define C1U(E, ci) { float v; bool s; \
                v = fadd(v2q[k][(ci)*4+0], E.x); s = v>=4.5f; v2q[k][(ci)*4+0] = s?0.f:v; cb0 |= (unsigned)s; \
                v = fadd(v2q[k][(ci)*4+1], E.y); s = v>=4.5f; v2q[k][(ci)*4+1] = s?0.f:v; cb1 |= (unsigned)s; \
                v = fadd(v2q[k][(ci)*4+2], E.z); s = v>=4.5f; v2q[k][(ci)*4+2] = s?0.f:v; cb2 |= (unsigned)s; \
                v = fadd(v2q[k][(ci)*4+3], E.w); s = v>=4.5f; v2q[k][(ci)*4+3] = s?0.f:v; cb3 |= (unsigned)s; }
            C1U(e00, 0) C1U(e01, 1) C1U(e10, 2) C1U(e11, 3)
            #undef C1U
            int pw = pi1[k]; unsigned bt = pb1[k];
            if (cb0) atomicOr(&p1[pw],      bt);
            if (cb1) atomicOr(&p1[13 + pw], bt);
            if (cb2) atomicOr(&p1[26 + pw], bt);
            if (cb3) atomicOr(&p1[39 + pw], bt);
        }
    }
}

__device__ __forceinline__ void conv2_step(const unsigned* p1, unsigned* p2,
        float (&v3s)[5][2], const float2* lut2,
        const int (&i2c)[5], const int (&lb2)[5], const int (&p2w2)[5],
        const unsigned (&js2)[5], const unsigned (&b20)[5], const unsigned (&b21)[5],
        const bool (&ok2)[5]) {
    #pragma unroll
    for (int k = 0; k < 5; ++k) {
        if (ok2[k]) {
            float accA = 0.f, accB = 0.f;
            #pragma unroll
            for (int ic = 0; ic < 4; ++ic)
                #pragma unroll
                for (int ki = 0; ki < 3; ++ki) {
                    unsigned row = p1[ic * 13 + i2c[k] + ki];
                    unsigned idx = UBFE(row, js2[k], 4);
                    float2 e = lut2[lb2[k] + (ic * 3 + ki) * 16 + idx];
                    accA = fadd(accA, e.x);
                    accB = fadd(accB, e.y);
                }
            float va = fadd(v3s[k][0], accA);
            float vb = fadd(v3s[k][1], accB);
            bool sa = va >= 1.0f, sb = vb >= 1.0f;
            v3s[k][0] = sa ? 0.f : va;
            v3s[k][1] = sb ? 0.f : vb;
            unsigned orm = (sa ? b20[k] : 0u) | (sb ? b21[k] : 0u);
            if (orm) atomicOr(&p2[p2w2[k]], orm);
        }
    }
}

__device__ __forceinline__ void conv3_step(const unsigned* p2, const float* lut3,
                                           float& v4, float& pred, int rr3, int cc3) {
    float acc = 0.f;
    #pragma unroll
    for (int ic = 0; ic < 4; ++ic)
        #pragma unroll
        for (int ki = 0; ki < 3; ++ki) {
            unsigned row = p2[ic * 6 + rr3 + ki];
            unsigned idx = UBFE(row, cc3, 3);
            acc = fadd(acc, lut3[(ic * 3 + ki) * 8 + idx]);
        }
    v4 = fadd(v4, fmul(fsub(acc, v4), 0.5f));
    if (v4 >= 1.0f) { pred += 1.f; v4 = 0.f; }
}

// 2 samples per wave, 4 waves = 8 samples per block. Barrier-free main loop,
// 3 in-wave fences per step; chains A/B interleave to hide LDS latency.
template<bool CACHE>
__global__ __launch_bounds__(256, 2) void sim_kernel(const float* __restrict__ x,
        int nbatch,
        const float* __restrict__ w1g, const float* __restrict__ w2g,
        const float* __restrict__ w3g, GaussW gw,
        const unsigned int* __restrict__ dmaxp,
        const float* __restrict__ dcache,
        float* __restrict__ out) {
    __shared__ __align__(16) float4 lut[512];   // conv1 LUT (shared across block)
    __shared__ __align__(8)  float2 lut2[768];  // conv2 row-pair LUT
    __shared__ float lut3[96];                  // conv3 row LUT
    __shared__ float wts[216];
    __shared__ __align__(16) float dnS[8][800]; // per-sample DoG (pad to 800)
    __shared__ unsigned s1S[8][28];
    __shared__ unsigned p1S[8][52];
    __shared__ unsigned p2S[8][24];

    int tid = threadIdx.x;
    int lane = tid & 63, wv = tid >> 6;
    int b8 = blockIdx.x * 8;
    int bA = b8 + 2 * wv, bB = bA + 1;
    int bAc = bA < nbatch ? bA : nbatch - 1;
    int bBc = bB < nbatch ? bB : nbatch - 1;

    // ---------- block prologue (only barriers) ----------
    if (!CACHE) {
        float* scr = (float*)lut;   // 2048 floats >= 2*784 scratch
        for (int s = 0; s < 8; ++s) {
            int bb = b8 + s; if (bb >= nbatch) bb = nbatch - 1;
            dog_sample(x, bb, nbatch, gw, scr, scr + HW, &dnS[s][0], tid);
        }
    }
    if (tid < 36)  wts[tid]       = w1g[tid];
    if (tid < 144) wts[36 + tid]  = w2g[tid];
    if (tid < 36)  wts[180 + tid] = w3g[tid];
    __syncthreads();
    for (int e = tid; e < 512; e += 256) {
        float a0 = 0.f, a1 = 0.f, a2 = 0.f, a3 = 0.f;
        #pragma unroll
        for (int k = 0; k < 9; ++k) {
            bool bit = (e >> k) & 1;
            a0 = fadd(a0, bit ? wts[k]      : 0.0f);
            a1 = fadd(a1, bit ? wts[9 + k]  : 0.0f);
            a2 = fadd(a2, bit ? wts[18 + k] : 0.0f);
            a3 = fadd(a3, bit ? wts[27 + k] : 0.0f);
        }
        lut[e] = make_float4(a0, a1, a2, a3);
    }
    for (int e = tid; e < 768; e += 256) {
        int rowIdx = e >> 4, idx = e & 15;
        int cout = rowIdx / 12, rem = rowIdx - cout * 12;
        int ic = rem / 3, ki = rem - ic * 3;
        const float* wb = &wts[36 + cout * 36 + ic * 9 + ki * 3];
        float xx = 0.f, yy = 0.f;
        #pragma unroll
        for (int kk = 0; kk < 3; ++kk) {
            xx = fadd(xx, ((idx >> kk) & 1) ? wb[kk] : 0.0f);
            yy = fadd(yy, ((idx >> (kk + 1)) & 1) ? wb[kk] : 0.0f);
        }
        lut2[e] = make_float2(xx, yy);
    }
    if (tid < 96) {
        int ric = tid >> 3, idx = tid & 7;
        int ic = ric / 3, ki = ric - ic * 3;
        const float* wb = &wts[180 + ic * 9 + ki * 3];
        float xx = 0.f;
        #pragma unroll
        for (int kk = 0; kk < 3; ++kk)
            xx = fadd(xx, ((idx >> kk) & 1) ? wb[kk] : 0.0f);
        lut3[tid] = xx;
    }
    __syncthreads();

    // ---------- per-wave init ----------
    float* dnA = dnS[2 * wv];     float* dnB = dnS[2 * wv + 1];
    unsigned* s1A = s1S[2 * wv];  unsigned* s1B = s1S[2 * wv + 1];
    unsigned* p1A = p1S[2 * wv];  unsigned* p1B = p1S[2 * wv + 1];
    unsigned* p2A = p2S[2 * wv];  unsigned* p2B = p2S[2 * wv + 1];

    float dmaxv = __uint_as_float(*dmaxp);
    if (CACHE) {
        const float* da = dcache + (size_t)bAc * HW;
        const float* db = dcache + (size_t)bBc * HW;
        for (int r = 0; r < 13; ++r) {
            int p = (r << 6) + lane;
            if (p < HW) {
                dnA[p] = __fdiv_rn(da[p], dmaxv);
                dnB[p] = __fdiv_rn(db[p], dmaxv);
            }
        }
    } else {
        for (int r = 0; r < 13; ++r) {
            int p = (r << 6) + lane;
            if (p < HW) {
                dnA[p] = __fdiv_rn(dnA[p], dmaxv);
                dnB[p] = __fdiv_rn(dnB[p], dmaxv);
            }
        }
    }
    if (lane < 16) { dnA[HW + lane] = 0.f; dnB[HW + lane] = 0.f; }
    if (lane < 52) { p1A[lane] = 0u; p1B[lane] = 0u; }
    if (lane < 24) { p2A[lane] = 0u; p2B[lane] = 0u; }
    WFENCE();

    // ---- per-lane geometry (shared by both samples) ----
    int sr1[3], pi1[3]; unsigned sh1[3], pb1[3]; bool ok1[3];
    #pragma unroll
    for (int k = 0; k < 3; ++k) {
        int q = lane + (k << 6);
        ok1[k] = q < 169;
        if (q >= 169) q = 0;
        int pi = q / 13, pj = q - pi * 13;
        sr1[k] = 2 * pi; sh1[k] = (unsigned)(2 * pj);
        pi1[k] = pi; pb1[k] = 1u << (pj + 1);
    }
    int i2c[5], lb2[5], p2w2[5]; unsigned js2[5], b20[5], b21[5]; bool ok2[5];
    #pragma unroll
    for (int k = 0; k < 5; ++k) {
        int m = lane + (k << 6);
        ok2[k] = m < 264;
        if (m >= 264) m = 0;
        int row = m / 6, sub = m - row * 6;
        int j0 = (sub < 5) ? 2 * sub : 10;
        int c = row / 11, i2 = row - c * 11;
        i2c[k] = i2; js2[k] = (unsigned)(j0 + 1); lb2[k] = c * 192;
        p2w2[k] = c * 6 + ((i2 + 1) >> 1);
        b20[k] = 1u << (j0 >> 1);
        b21[k] = (sub < 5) ? (2u << (j0 >> 1)) : 0u;
    }
    int rr3 = (lane >> 2) & 3, cc3 = lane & 3;

    // ---- membranes (registers, 2 chains) ----
    float v2qA[3][16] = {}; float v2qB[3][16] = {};
    float v3sA[5][2] = {};  float v3sB[5][2] = {};
    float v1mA[14] = {};    float v1mB[14] = {};
    float v4A = 0.f, predA = 0.f, v4B = 0.f, predB = 0.f;

    #pragma unroll 1
    for (int t = 0; t < TSTEPS; ++t) {
        // ==== P1: conv3(t-1) | zero p2 | layer1(t), both samples ====
        if (t > 0 && lane < 16) {
            conv3_step(p2A, lut3, v4A, predA, rr3, cc3);
            conv3_step(p2B, lut3, v4B, predB, rr3, cc3);
        }
        // zero p2 AFTER conv3 reads (in-wave program order; DS ops in order)
        if (lane >= 16 && lane < 40) p2A[lane - 16] = 0u;
        else if (lane >= 40) p2B[lane - 40] = 0u;
        layer1_step(dnA, s1A, v1mA, lane);
        layer1_step(dnB, s1B, v1mB, lane);
        WFENCE();

        // ==== P2: conv1(t), both samples ====
        conv1_step(s1A, p1A, v2qA, lut, sr1, pi1, sh1, pb1, ok1);
        conv1_step(s1B, p1B, v2qB, lut, sr1, pi1, sh1, pb1, ok1);
        WFENCE();

        // ==== P3: conv2(t), both samples; then zero p1 ====
        conv2_step(p1A, p2A, v3sA, lut2, i2c, lb2, p2w2, js2, b20, b21, ok2);
        conv2_step(p1B, p2B, v3sB, lut2, i2c, lb2, p2w2, js2, b20, b21, ok2);
        if (lane < 52) { p1A[lane] = 0u; p1B[lane] = 0u; }
        WFENCE();
    }

    // ---- epilogue: conv3(29) + output ----
    if (lane < 16) {
        conv3_step(p2A, lut3, v4A, predA, rr3, cc3);
        conv3_step(p2B, lut3, v4B, predB, rr3, cc3);
        if (bA < nbatch) out[(size_t)bA * 16 + lane] = __fdiv_rn(predA, 30.0f);
        if (bB < nbatch) out[(size_t)bB * 16 + lane] = __fdiv_rn(predB, 30.0f);
    }
}

extern "C" void kernel_launch(void* const* d_in, const int* in_sizes, int n_in,
                              void* d_out, int out_size, void* d_ws, size_t ws_size,
                              hipStream_t stream) {
    const float* x  = (const float*)d_in[0];
    const float* w1 = (const float*)d_in[1];
    const float* w2 = (const float*)d_in[2];
    const float* w3 = (const float*)d_in[3];
    float* out = (float*)d_out;
    unsigned int* dmax = (unsigned int*)d_ws;
    float* dcache = (float*)((char*)d_ws + 16);

    int nbatch = in_sizes[0] / HW;
    size_t need = 16 + (size_t)nbatch * HW * sizeof(float);
    bool cache = ws_size >= need;
    int g4 = (nbatch + 3) / 4;
    int g8 = (nbatch + 7) / 8;

    // numpy-f32 Gaussian weights: exact f32 steps + correctly-rounded exp
    GaussW gw;
    {
        float fw[7];
        for (int k = 0; k < 7; ++k) {
            float iv = (float)(k - 3);
            float q = iv / 2.0f;
            float e = -0.5f * (q * q);
            fw[k] = (float)exp((double)e);
        }
        float s = 0.0f;
        for (int k = 0; k < 7; ++k) s += fw[k];
        for (int k = 0; k < 7; ++k) gw.w[k] = fw[k] / s;
    }

    hipLaunchKernelGGL(init_kernel, dim3(1), dim3(1), 0, stream, dmax);
    if (cache) {
        hipLaunchKernelGGL(dmax_kernel<true>, dim3(g4), dim3(256), 0, stream,
                           x, nbatch, gw, dmax, dcache);
        hipLaunchKernelGGL(sim_kernel<true>, dim3(g8), dim3(256), 0, stream,
                           x, nbatch, w1, w2, w3, gw, dmax, dcache, out);
    } else {
        hipLaunchKernelGGL(dmax_kernel<false>, dim3(g4), dim3(256), 0, stream,
                           x, nbatch, gw, dmax, dcache);
        hipLaunchKernelGGL(sim_kernel<false>, dim3(g8), dim3(256), 0, stream,
                           x, nbatch, w1, w2, w3, gw, dmax, dcache, out);
    }
}

// Round 12
// 313.225 us; speedup vs baseline: 1.2815x; 1.2724x over previous
//
#include <hip/hip_runtime.h>
#include <math.h>

#define HW 784      // 28*28
#define TSTEPS 30
#define TCHUNK 10   // steps per layer-major chunk (30 = 3 chunks)

struct GaussW { float w[7]; };

// Exact-rounded f32 ops (never fused/contracted) to bitwise-match numpy f32.
__device__ __forceinline__ float fadd(float a, float b) { return __fadd_rn(a, b); }
__device__ __forceinline__ float fmul(float a, float b) { return __fmul_rn(a, b); }
__device__ __forceinline__ float fsub(float a, float b) { return __fsub_rn(a, b); }

#if defined(__has_builtin)
#  if __has_builtin(__builtin_amdgcn_ubfe)
#    define UBFE(x, o, w) __builtin_amdgcn_ubfe((unsigned)(x), (unsigned)(o), (unsigned)(w))
#  endif
#endif
#ifndef UBFE
#  define UBFE(x, o, w) (((unsigned)(x) >> (o)) & ((1u << (w)) - 1u))
#endif

// In-wave fence: drains LDS ops + compiler barrier (cross-lane write->read).
#define WFENCE() asm volatile("s_waitcnt lgkmcnt(0)" ::: "memory")

__device__ __forceinline__ int refl(int i, int n) {
    if (i < 0) return -i - 1;
    if (i >= n) return 2 * n - 1 - i;
    return i;
}

// Block-wide DoG (fallback path only), bit-exact numpy-f32 order.
__device__ void dog_sample(const float* __restrict__ x, int b, int nbatch,
                           const GaussW gw, float* g, float* t,
                           float* dout, int tid) {
    for (int p = tid; p < HW; p += 256) {
        float acc = fmul(gw.w[0], x[(size_t)refl(b - 3, nbatch) * HW + p]);
        #pragma unroll
        for (int k = 1; k < 7; ++k)
            acc = fadd(acc, fmul(gw.w[k], x[(size_t)refl(b - 3 + k, nbatch) * HW + p]));
        float h = fmul(gw.w[0], acc);
        #pragma unroll
        for (int k = 1; k < 7; ++k)
            h = fadd(h, fmul(gw.w[k], acc));
        g[p] = h;
    }
    __syncthreads();
    for (int p = tid; p < HW; p += 256) {
        int i = p / 28, j = p - (p / 28) * 28;
        float acc = fmul(gw.w[0], g[refl(i - 3, 28) * 28 + j]);
        #pragma unroll
        for (int k = 1; k < 7; ++k)
            acc = fadd(acc, fmul(gw.w[k], g[refl(i - 3 + k, 28) * 28 + j]));
        t[p] = acc;
    }
    __syncthreads();
    for (int p = tid; p < HW; p += 256) {
        int i = p / 28, j = p - (p / 28) * 28;
        float acc = fmul(gw.w[0], t[i * 28 + refl(j - 3, 28)]);
        #pragma unroll
        for (int k = 1; k < 7; ++k)
            acc = fadd(acc, fmul(gw.w[k], t[i * 28 + refl(j - 3 + k, 28)]));
        dout[p] = fabsf(fsub(acc, x[(size_t)b * HW + p]));
    }
    __syncthreads();
}

__global__ void init_kernel(unsigned int* dmax) { *dmax = 0u; }

// Wave-per-sample DoG + global max (+ optional dcache write). No barriers.
template<bool CACHE>
__global__ __launch_bounds__(256) void dmax_kernel(const float* __restrict__ x,
                                                   int nbatch, GaussW gw,
                                                   unsigned int* __restrict__ dmax,
                                                   float* __restrict__ dcache) {
    __shared__ float gS[4][HW];
    __shared__ float tS[4][HW];
    int tid = threadIdx.x;
    int lane = tid & 63, wv = tid >> 6;
    int b = blockIdx.x * 4 + wv;
    int bs = b < nbatch ? b : nbatch - 1;
    float* g = gS[wv];
    float* t = tS[wv];
    const float* xb = x + (size_t)bs * HW;
    const float* xr[7];
    #pragma unroll
    for (int k = 0; k < 7; ++k)
        xr[k] = x + (size_t)refl(bs - 3 + k, nbatch) * HW;

    for (int r = 0; r < 13; ++r) {
        int p = (r << 6) + lane;
        if (p < HW) {
            float acc = fmul(gw.w[0], xr[0][p]);
            #pragma unroll
            for (int k = 1; k < 7; ++k)
                acc = fadd(acc, fmul(gw.w[k], xr[k][p]));
            float h = fmul(gw.w[0], acc);
            #pragma unroll
            for (int k = 1; k < 7; ++k)
                h = fadd(h, fmul(gw.w[k], acc));
            g[p] = h;
        }
    }
    WFENCE();
    for (int r = 0; r < 13; ++r) {
        int p = (r << 6) + lane;
        if (p < HW) {
            int i = p / 28, j = p - (p / 28) * 28;
            float acc = fmul(gw.w[0], g[refl(i - 3, 28) * 28 + j]);
            #pragma unroll
            for (int k = 1; k < 7; ++k)
                acc = fadd(acc, fmul(gw.w[k], g[refl(i - 3 + k, 28) * 28 + j]));
            t[p] = acc;
        }
    }
    WFENCE();
    float mx = 0.f;
    for (int r = 0; r < 13; ++r) {
        int p = (r << 6) + lane;
        if (p < HW) {
            int i = p / 28, j = p - (p / 28) * 28;
            float acc = fmul(gw.w[0], t[i * 28 + refl(j - 3, 28)]);
            #pragma unroll
            for (int k = 1; k < 7; ++k)
                acc = fadd(acc, fmul(gw.w[k], t[i * 28 + refl(j - 3 + k, 28)]));
            float d = fabsf(fsub(acc, xb[p]));
            if (CACHE) dcache[(size_t)bs * HW + p] = d;
            mx = fmaxf(mx, d);
        }
    }
    #pragma unroll
    for (int off = 32; off; off >>= 1) mx = fmaxf(mx, __shfl_down(mx, off, 64));
    if (lane == 0) atomicMax(dmax, __float_as_uint(mx));  // d>=0: bit-max ok
}

// ---- per-phase building blocks (bit-exact, verified r9-r11) ----

__device__ __forceinline__ void conv1_step(const unsigned* s1, unsigned* p1,
        float (&v2q)[3][16], const float4* lut,
        const int (&sr1)[3], const int (&pi1)[3], const unsigned (&sh1)[3],
        const unsigned (&pb1)[3], const bool (&ok1)[3]) {
    #pragma unroll
    for (int k = 0; k < 3; ++k) {
        if (ok1[k]) {
            int sr = sr1[k];
            unsigned m0 = s1[sr], m1 = s1[sr + 1], m2 = s1[sr + 2], m3 = s1[sr + 3];
            unsigned sh = sh1[k];
            unsigned a = UBFE(m0, sh, 4), bq = UBFE(m1, sh, 4),
                     cq = UBFE(m2, sh, 4), dq = UBFE(m3, sh, 4);
            unsigned a7 = a & 7u, b7 = bq & 7u, c7 = cq & 7u, d7 = dq & 7u;
            unsigned a1 = a >> 1, b1 = bq >> 1, c1 = cq >> 1, d1 = dq >> 1;
            unsigned p00 = a7 | (b7 << 3) | (c7 << 6);
            unsigned p01 = a1 | (b1 << 3) | (c1 << 6);
            unsigned p10 = b7 | (c7 << 3) | (d7 << 6);
            unsigned p11 = b1 | (c1 << 3) | (d1 << 6);
            float4 e00 = lut[p00], e01 = lut[p01], e10 = lut[p10], e11 = lut[p11];
            unsigned cb0 = 0, cb1 = 0, cb2 = 0, cb3 = 0;
            #define C1U(E, ci) { float v; bool s; \
                v = fadd(v2q[k][(ci)*4+0], E.x); s = v>=4.5f; v2q[k][(ci)*4+0] = s?0.f:v; cb0 |= (unsigned)s; \
                v = fadd(v2q[k][(ci)*4+1], E.y); s = v>=4.5f; v2q[k][(ci)*4+1] = s?0.f:v; cb1 |= (unsigned)s; \
                v = fadd(v2q[k][(ci)*4+2], E.z); s = v>=4.5f; v2q[k][(ci)*4+2] = s?0.f:v; cb2 |= (unsigned)s; \
                v = fadd(v2q[k][(ci)*4+3], E.w); s = v>=4.5f; v2q[k][(ci)*4+3] = s?0.f:v; cb3 |= (unsigned)s; }
            C1U(e00, 0) C1U(e01, 1) C1U(e10, 2) C1U(e11, 3)
            #undef C1U
            int pw = pi1[k]; unsigned bt = pb1[k];
            if (cb0) atomicOr(&p1[pw],      bt);
            if (cb1) atomicOr(&p1[13 + pw], bt);
            if (cb2) atomicOr(&p1[26 + pw], bt);
            if (cb3) atomicOr(&p1[39 + pw], bt);
        }
    }
}

__device__ __forceinline__ void conv2_step(const unsigned* p1, unsigned* p2,
        float (&v3s)[5][2], const float2* lut2,
        const int (&i2c)[5], const int (&lb2)[5], const int (&p2w2)[5],
        const unsigned (&js2)[5], const unsigned (&b20)[5], const unsigned (&b21)[5],
        const bool (&ok2)[5]) {
    #pragma unroll
    for (int k = 0; k < 5; ++k) {
        if (ok2[k]) {
            float accA = 0.f, accB = 0.f;
            #pragma unroll
            for (int ic = 0; ic < 4; ++ic)
                #pragma unroll
                for (int ki = 0; ki < 3; ++ki) {
                    unsigned row = p1[ic * 13 + i2c[k] + ki];
                    unsigned idx = UBFE(row, js2[k], 4);
                    float2 e = lut2[lb2[k] + (ic * 3 + ki) * 16 + idx];
                    accA = fadd(accA, e.x);
                    accB = fadd(accB, e.y);
                }
            float va = fadd(v3s[k][0], accA);
            float vb = fadd(v3s[k][1], accB);
            bool sa = va >= 1.0f, sb = vb >= 1.0f;
            v3s[k][0] = sa ? 0.f : va;
            v3s[k][1] = sb ? 0.f : vb;
            unsigned orm = (sa ? b20[k] : 0u) | (sb ? b21[k] : 0u);
            if (orm) atomicOr(&p2[p2w2[k]], orm);
        }
    }
}

__device__ __forceinline__ void conv3_step(const unsigned* p2, const float* lut3,
                                           float& v4, float& pred, int rr3, int cc3) {
    float acc = 0.f;
    #pragma unroll
    for (int ic = 0; ic < 4; ++ic)
        #pragma unroll
        for (int ki = 0; ki < 3; ++ki) {
            unsigned row = p2[ic * 6 + rr3 + ki];
            unsigned idx = UBFE(row, cc3, 3);
            acc = fadd(acc, lut3[(ic * 3 + ki) * 8 + idx]);
        }
    v4 = fadd(v4, fmul(fsub(acc, v4), 0.5f));
    if (v4 >= 1.0f) { pred += 1.f; v4 = 0.f; }
}

// Layer-major chunked wave-per-sample simulation: fences only between layer
// loops (4 per chunk, 12 total) instead of per-step.
template<bool CACHE>
__global__ __launch_bounds__(256, 3) void sim_kernel(const float* __restrict__ x,
        int nbatch,
        const float* __restrict__ w1g, const float* __restrict__ w2g,
        const float* __restrict__ w3g, GaussW gw,
        const unsigned int* __restrict__ dmaxp,
        const float* __restrict__ dcache,
        float* __restrict__ out) {
    __shared__ __align__(16) float4 lut[512];   // conv1 LUT (block-shared)
    __shared__ __align__(8)  float2 lut2[768];  // conv2 row-pair LUT
    __shared__ float lut3[96];                  // conv3 row LUT
    __shared__ float wts[216];
    // per-wave chunk masks: s1m[TCHUNK][28] | p1m[TCHUNK][52] | p2m[TCHUNK][24]
    __shared__ unsigned maskS[4][TCHUNK * 104];

    int tid = threadIdx.x;
    int lane = tid & 63, wv = tid >> 6;
    int b4 = blockIdx.x * 4;
    int b = b4 + wv;
    int bc = b < nbatch ? b : nbatch - 1;

    // ---------- block prologue (the only __syncthreads) ----------
    if (!CACHE) {
        float* scr = (float*)lut;   // 2048 floats >= 2*784 scratch
        for (int s = 0; s < 4; ++s) {
            int bb = b4 + s; if (bb >= nbatch) bb = nbatch - 1;
            dog_sample(x, bb, nbatch, gw, scr, scr + HW, (float*)&maskS[s][0], tid);
        }
    }
    if (tid < 36)  wts[tid]       = w1g[tid];
    if (tid < 144) wts[36 + tid]  = w2g[tid];
    if (tid < 36)  wts[180 + tid] = w3g[tid];
    __syncthreads();
    for (int e = tid; e < 512; e += 256) {
        float a0 = 0.f, a1 = 0.f, a2 = 0.f, a3 = 0.f;
        #pragma unroll
        for (int k = 0; k < 9; ++k) {
            bool bit = (e >> k) & 1;
            a0 = fadd(a0, bit ? wts[k]      : 0.0f);
            a1 = fadd(a1, bit ? wts[9 + k]  : 0.0f);
            a2 = fadd(a2, bit ? wts[18 + k] : 0.0f);
            a3 = fadd(a3, bit ? wts[27 + k] : 0.0f);
        }
        lut[e] = make_float4(a0, a1, a2, a3);
    }
    for (int e = tid; e < 768; e += 256) {
        int rowIdx = e >> 4, idx = e & 15;
        int cout = rowIdx / 12, rem = rowIdx - cout * 12;
        int ic = rem / 3, ki = rem - ic * 3;
        const float* wb = &wts[36 + cout * 36 + ic * 9 + ki * 3];
        float xx = 0.f, yy = 0.f;
        #pragma unroll
        for (int kk = 0; kk < 3; ++kk) {
            xx = fadd(xx, ((idx >> kk) & 1) ? wb[kk] : 0.0f);
            yy = fadd(yy, ((idx >> (kk + 1)) & 1) ? wb[kk] : 0.0f);
        }
        lut2[e] = make_float2(xx, yy);
    }
    if (tid < 96) {
        int ric = tid >> 3, idx = tid & 7;
        int ic = ric / 3, ki = ric - ic * 3;
        const float* wb = &wts[180 + ic * 9 + ki * 3];
        float xx = 0.f;
        #pragma unroll
        for (int kk = 0; kk < 3; ++kk)
            xx = fadd(xx, ((idx >> kk) & 1) ? wb[kk] : 0.0f);
        lut3[tid] = xx;
    }
    __syncthreads();

    // ---------- per-wave: load dn into registers ----------
    float dmaxv = __uint_as_float(*dmaxp);
    float dnr[14];
    if (CACHE) {
        const float* dcb = dcache + (size_t)bc * HW;
        #pragma unroll
        for (int r = 0; r < 14; ++r) {
            int p = r * 56 + (lane < 56 ? lane : 0);   // stay in-bounds
            float d = dcb[p];
            dnr[r] = (lane < 56) ? __fdiv_rn(d, dmaxv) : 0.f;
        }
    } else {
        const float* dptr = (const float*)&maskS[wv][0];
        #pragma unroll
        for (int r = 0; r < 14; ++r) {
            int p = r * 56 + (lane < 56 ? lane : 0);
            float d = dptr[p];
            dnr[r] = (lane < 56) ? __fdiv_rn(d, dmaxv) : 0.f;
        }
        WFENCE();   // finish LDS reads before masks clobber the region
    }

    unsigned* s1m = &maskS[wv][0];                // [TCHUNK][28]
    unsigned* p1m = &maskS[wv][TCHUNK * 28];      // [TCHUNK][52]
    unsigned* p2m = &maskS[wv][TCHUNK * 80];      // [TCHUNK][24]

    // ---------- per-lane geometry ----------
    int sr1[3], pi1[3]; unsigned sh1[3], pb1[3]; bool ok1[3];
    #pragma unroll
    for (int k = 0; k < 3; ++k) {
        int q = lane + (k << 6);
        ok1[k] = q < 169;
        if (q >= 169) q = 0;
        int pi = q / 13, pj = q - pi * 13;
        sr1[k] = 2 * pi; sh1[k] = (unsigned)(2 * pj);
        pi1[k] = pi; pb1[k] = 1u << (pj + 1);
    }
    int i2c[5], lb2[5], p2w2[5]; unsigned js2[5], b20[5], b21[5]; bool ok2[5];
    #pragma unroll
    for (int k = 0; k < 5; ++k) {
        int m = lane + (k << 6);
        ok2[k] = m < 264;
        if (m >= 264) m = 0;
        int row = m / 6, sub = m - row * 6;
        int j0 = (sub < 5) ? 2 * sub : 10;
        int c = row / 11, i2 = row - c * 11;
        i2c[k] = i2; js2[k] = (unsigned)(j0 + 1); lb2[k] = c * 192;
        p2w2[k] = c * 6 + ((i2 + 1) >> 1);
        b20[k] = 1u << (j0 >> 1);
        b21[k] = (sub < 5) ? (2u << (j0 >> 1)) : 0u;
    }
    int rr3 = (lane >> 2) & 3, cc3 = lane & 3;

    // ---------- membranes (registers) ----------
    float v2q[3][16] = {};
    float v3s[5][2] = {};
    float v1m[14] = {};
    float v4 = 0.f, pred = 0.f;

    // ---------- layer-major chunked loop ----------
    #pragma unroll 1
    for (int c = 0; c < TSTEPS / TCHUNK; ++c) {
        // zero p1m/p2m chunk buffers (ordered before atomicOrs by in-wave DS order)
        #pragma unroll
        for (int w = 0; w < (TCHUNK * 52 + 63) / 64; ++w) {
            int idx = lane + (w << 6);
            if (idx < TCHUNK * 52) p1m[idx] = 0u;
        }
        #pragma unroll
        for (int w = 0; w < (TCHUNK * 24 + 63) / 64; ++w) {
            int idx = lane + (w << 6);
            if (idx < TCHUNK * 24) p2m[idx] = 0u;
        }
        // ---- layer1 x TCHUNK (autonomous; no LDS reads) ----
        #pragma unroll 1
        for (int tt = 0; tt < TCHUNK; ++tt) {
            unsigned* s1 = s1m + tt * 28;
            #pragma unroll
            for (int r = 0; r < 14; ++r) {
                float v = fadd(v1m[r], dnr[r]);
                bool spk = (lane < 56) && (v >= 4.5f);
                v1m[r] = spk ? 0.f : v;
                unsigned long long bal = __ballot(spk);
                if (lane < 2)
                    s1[2 * r + lane] = (unsigned)(lane ? (bal >> 28) : bal) & 0x0FFFFFFFu;
            }
        }
        WFENCE();
        // ---- conv1 x TCHUNK ----
        #pragma unroll 1
        for (int tt = 0; tt < TCHUNK; ++tt)
            conv1_step(s1m + tt * 28, p1m + tt * 52, v2q, lut, sr1, pi1, sh1, pb1, ok1);
        WFENCE();
        // ---- conv2 x TCHUNK ----
        #pragma unroll 1
        for (int tt = 0; tt < TCHUNK; ++tt)
            conv2_step(p1m + tt * 52, p2m + tt * 24, v3s, lut2, i2c, lb2, p2w2,
                       js2, b20, b21, ok2);
        WFENCE();
        // ---- conv3 + LIF x TCHUNK ----
        if (lane < 16) {
            #pragma unroll 1
            for (int tt = 0; tt < TCHUNK; ++tt)
                conv3_step(p2m + tt * 24, lut3, v4, pred, rr3, cc3);
        }
        WFENCE();
    }

    if (lane < 16 && b < nbatch)
        out[(size_t)b * 16 + lane] = __fdiv_rn(pred, 30.0f);
}

extern "C" void kernel_launch(void* const* d_in, const int* in_sizes, int n_in,
                              void* d_out, int out_size, void* d_ws, size_t ws_size,
                              hipStream_t stream) {
    const float* x  = (const float*)d_in[0];
    const float* w1 = (const float*)d_in[1];
    const float* w2 = (const float*)d_in[2];
    const float* w3 = (const float*)d_in[3];
    float* out = (float*)d_out;
    unsigned int* dmax = (unsigned int*)d_ws;
    float* dcache = (float*)((char*)d_ws + 16);

    int nbatch = in_sizes[0] / HW;
    size_t need = 16 + (size_t)nbatch * HW * sizeof(float);
    bool cache = ws_size >= need;
    int g4 = (nbatch + 3) / 4;

    // numpy-f32 Gaussian weights: exact f32 steps + correctly-rounded exp
    GaussW gw;
    {
        float fw[7];
        for (int k = 0; k < 7; ++k) {
            float iv = (float)(k - 3);
            float q = iv / 2.0f;
            float e = -0.5f * (q * q);
            fw[k] = (float)exp((double)e);
        }
        float s = 0.0f;
        for (int k = 0; k < 7; ++k) s += fw[k];
        for (int k = 0; k < 7; ++k) gw.w[k] = fw[k] / s;
    }

    hipLaunchKernelGGL(init_kernel, dim3(1), dim3(1), 0, stream, dmax);
    if (cache) {
        hipLaunchKernelGGL(dmax_kernel<true>, dim3(g4), dim3(256), 0, stream,
                           x, nbatch, gw, dmax, dcache);
        hipLaunchKernelGGL(sim_kernel<true>, dim3(g4), dim3(256), 0, stream,
                           x, nbatch, w1, w2, w3, gw, dmax, dcache, out);
    } else {
        hipLaunchKernelGGL(dmax_kernel<false>, dim3(g4), dim3(256), 0, stream,
                           x, nbatch, gw, dmax, dcache);
        hipLaunchKernelGGL(sim_kernel<false>, dim3(g4), dim3(256), 0, stream,
                           x, nbatch, w1, w2, w3, gw, dmax, dcache, out);
    }
}

// Round 13
// 269.423 us; speedup vs baseline: 1.4898x; 1.1626x over previous
//
#include <hip/hip_runtime.h>
#include <math.h>

#define HW 784      // 28*28
#define TSTEPS 30
#define TCHUNK 10   // steps per layer-major chunk (30 = 3 chunks)

struct GaussW { float w[7]; };

// Exact-rounded f32 ops (never fused/contracted) to bitwise-match numpy f32.
__device__ __forceinline__ float fadd(float a, float b) { return __fadd_rn(a, b); }
__device__ __forceinline__ float fmul(float a, float b) { return __fmul_rn(a, b); }
__device__ __forceinline__ float fsub(float a, float b) { return __fsub_rn(a, b); }

#if defined(__has_builtin)
#  if __has_builtin(__builtin_amdgcn_ubfe)
#    define UBFE(x, o, w) __builtin_amdgcn_ubfe((unsigned)(x), (unsigned)(o), (unsigned)(w))
#  endif
#endif
#ifndef UBFE
#  define UBFE(x, o, w) (((unsigned)(x) >> (o)) & ((1u << (w)) - 1u))
#endif

// In-wave fence (dmax kernel only).
#define WFENCE() asm volatile("s_waitcnt lgkmcnt(0)" ::: "memory")

__device__ __forceinline__ int refl(int i, int n) {
    if (i < 0) return -i - 1;
    if (i >= n) return 2 * n - 1 - i;
    return i;
}

// Block-wide DoG (fallback path only), bit-exact numpy-f32 order.
__device__ void dog_sample(const float* __restrict__ x, int b, int nbatch,
                           const GaussW gw, float* g, float* t,
                           float* dout, int tid) {
    for (int p = tid; p < HW; p += 256) {
        float acc = fmul(gw.w[0], x[(size_t)refl(b - 3, nbatch) * HW + p]);
        #pragma unroll
        for (int k = 1; k < 7; ++k)
            acc = fadd(acc, fmul(gw.w[k], x[(size_t)refl(b - 3 + k, nbatch) * HW + p]));
        float h = fmul(gw.w[0], acc);
        #pragma unroll
        for (int k = 1; k < 7; ++k)
            h = fadd(h, fmul(gw.w[k], acc));
        g[p] = h;
    }
    __syncthreads();
    for (int p = tid; p < HW; p += 256) {
        int i = p / 28, j = p - (p / 28) * 28;
        float acc = fmul(gw.w[0], g[refl(i - 3, 28) * 28 + j]);
        #pragma unroll
        for (int k = 1; k < 7; ++k)
            acc = fadd(acc, fmul(gw.w[k], g[refl(i - 3 + k, 28) * 28 + j]));
        t[p] = acc;
    }
    __syncthreads();
    for (int p = tid; p < HW; p += 256) {
        int i = p / 28, j = p - (p / 28) * 28;
        float acc = fmul(gw.w[0], t[i * 28 + refl(j - 3, 28)]);
        #pragma unroll
        for (int k = 1; k < 7; ++k)
            acc = fadd(acc, fmul(gw.w[k], t[i * 28 + refl(j - 3 + k, 28)]));
        dout[p] = fabsf(fsub(acc, x[(size_t)b * HW + p]));
    }
    __syncthreads();
}

__global__ void init_kernel(unsigned int* dmax) { *dmax = 0u; }

// Wave-per-sample DoG + global max (+ optional dcache write). No barriers.
template<bool CACHE>
__global__ __launch_bounds__(256) void dmax_kernel(const float* __restrict__ x,
                                                   int nbatch, GaussW gw,
                                                   unsigned int* __restrict__ dmax,
                                                   float* __restrict__ dcache) {
    __shared__ float gS[4][HW];
    __shared__ float tS[4][HW];
    int tid = threadIdx.x;
    int lane = tid & 63, wv = tid >> 6;
    int b = blockIdx.x * 4 + wv;
    int bs = b < nbatch ? b : nbatch - 1;
    float* g = gS[wv];
    float* t = tS[wv];
    const float* xb = x + (size_t)bs * HW;
    const float* xr[7];
    #pragma unroll
    for (int k = 0; k < 7; ++k)
        xr[k] = x + (size_t)refl(bs - 3 + k, nbatch) * HW;

    for (int r = 0; r < 13; ++r) {
        int p = (r << 6) + lane;
        if (p < HW) {
            float acc = fmul(gw.w[0], xr[0][p]);
            #pragma unroll
            for (int k = 1; k < 7; ++k)
                acc = fadd(acc, fmul(gw.w[k], xr[k][p]));
            float h = fmul(gw.w[0], acc);
            #pragma unroll
            for (int k = 1; k < 7; ++k)
                h = fadd(h, fmul(gw.w[k], acc));
            g[p] = h;
        }
    }
    WFENCE();
    for (int r = 0; r < 13; ++r) {
        int p = (r << 6) + lane;
        if (p < HW) {
            int i = p / 28, j = p - (p / 28) * 28;
            float acc = fmul(gw.w[0], g[refl(i - 3, 28) * 28 + j]);
            #pragma unroll
            for (int k = 1; k < 7; ++k)
                acc = fadd(acc, fmul(gw.w[k], g[refl(i - 3 + k, 28) * 28 + j]));
            t[p] = acc;
        }
    }
    WFENCE();
    float mx = 0.f;
    for (int r = 0; r < 13; ++r) {
        int p = (r << 6) + lane;
        if (p < HW) {
            int i = p / 28, j = p - (p / 28) * 28;
            float acc = fmul(gw.w[0], t[i * 28 + refl(j - 3, 28)]);
            #pragma unroll
            for (int k = 1; k < 7; ++k)
                acc = fadd(acc, fmul(gw.w[k], t[i * 28 + refl(j - 3 + k, 28)]));
            float d = fabsf(fsub(acc, xb[p]));
            if (CACHE) dcache[(size_t)bs * HW + p] = d;
            mx = fmaxf(mx, d);
        }
    }
    #pragma unroll
    for (int off = 32; off; off >>= 1) mx = fmaxf(mx, __shfl_down(mx, off, 64));
    if (lane == 0) atomicMax(dmax, __float_as_uint(mx));  // d>=0: bit-max ok
}

// Block-per-sample, layer-major chunks: 4 barriers per chunk, 12 in the loop.
template<bool CACHE>
__global__ __launch_bounds__(256, 6) void sim_kernel(const float* __restrict__ x,
        int nbatch,
        const float* __restrict__ w1g, const float* __restrict__ w2g,
        const float* __restrict__ w3g, GaussW gw,
        const unsigned int* __restrict__ dmaxp,
        const float* __restrict__ dcache,
        float* __restrict__ out) {
    __shared__ __align__(16) float4 lut[512];   // conv1 LUT (4ch); DoG scratch pre-build
    __shared__ __align__(8)  float2 lut2[768];  // conv2 row-pair LUT
    __shared__ float lut3[96];                  // conv3 row LUT
    __shared__ float wts[216];
    __shared__ unsigned s1m[TCHUNK * 28];       // spike rows per chunk-step
    __shared__ unsigned p1m[TCHUNK * 52];       // pooled-1 masks [4c][13r], bits<<1
    __shared__ unsigned p2m[TCHUNK * 24];       // pooled-2 masks [4c][6r]

    int tid = threadIdx.x;
    int b = blockIdx.x;                          // grid = nbatch
    if (b >= nbatch) b = nbatch - 1;

    // ---------------- prologue ----------------
    if (tid < 36)  wts[tid]       = w1g[tid];
    if (tid < 144) wts[36 + tid]  = w2g[tid];
    if (tid < 36)  wts[180 + tid] = w3g[tid];

    float dmaxv = __uint_as_float(*dmaxp);
    float dnr[4];
    if (CACHE) {
        const float* dcb = dcache + (size_t)b * HW;
        #pragma unroll
        for (int k = 0; k < 4; ++k) {
            int p = tid + (k << 8);
            dnr[k] = (p < HW) ? __fdiv_rn(dcb[p], dmaxv) : 0.f;
        }
    } else {
        float* scr = (float*)lut;                // 2048 floats >= 2*784
        float* dnbuf = (float*)s1m;              // 1040 words >= 784
        dog_sample(x, b, nbatch, gw, scr, scr + HW, dnbuf, tid);
        #pragma unroll
        for (int k = 0; k < 4; ++k) {
            int p = tid + (k << 8);
            dnr[k] = (p < HW) ? __fdiv_rn(dnbuf[p], dmaxv) : 0.f;
        }
    }
    __syncthreads();

    // build LUTs + zero all masks
    for (int e = tid; e < 512; e += 256) {
        float a0 = 0.f, a1 = 0.f, a2 = 0.f, a3 = 0.f;
        #pragma unroll
        for (int k = 0; k < 9; ++k) {
            bool bit = (e >> k) & 1;
            a0 = fadd(a0, bit ? wts[k]      : 0.0f);
            a1 = fadd(a1, bit ? wts[9 + k]  : 0.0f);
            a2 = fadd(a2, bit ? wts[18 + k] : 0.0f);
            a3 = fadd(a3, bit ? wts[27 + k] : 0.0f);
        }
        lut[e] = make_float4(a0, a1, a2, a3);
    }
    for (int e = tid; e < 768; e += 256) {
        int rowIdx = e >> 4, idx = e & 15;
        int cout = rowIdx / 12, rem = rowIdx - cout * 12;
        int ic = rem / 3, ki = rem - ic * 3;
        const float* wb = &wts[36 + cout * 36 + ic * 9 + ki * 3];
        float xx = 0.f, yy = 0.f;
        #pragma unroll
        for (int kk = 0; kk < 3; ++kk) {
            xx = fadd(xx, ((idx >> kk) & 1) ? wb[kk] : 0.0f);
            yy = fadd(yy, ((idx >> (kk + 1)) & 1) ? wb[kk] : 0.0f);
        }
        lut2[e] = make_float2(xx, yy);
    }
    if (tid < 96) {
        int ric = tid >> 3, idx = tid & 7;
        int ic = ric / 3, ki = ric - ic * 3;
        const float* wb = &wts[180 + ic * 9 + ki * 3];
        float xx = 0.f;
        #pragma unroll
        for (int kk = 0; kk < 3; ++kk)
            xx = fadd(xx, ((idx >> kk) & 1) ? wb[kk] : 0.0f);
        lut3[tid] = xx;
    }
    #pragma unroll
    for (int j = 0; j < 5; ++j) {
        int idx = tid + (j << 8);
        if (idx < TCHUNK * 104) {
            if (idx < 280) s1m[idx] = 0u;
            else if (idx < 800) p1m[idx - 280] = 0u;
            else p2m[idx - 800] = 0u;
        }
    }
    __syncthreads();

    // ---------------- fixed per-thread geometry ----------------
    // layer1: pixels e = tid + 256k (k<4; k=3 only tid<16)
    int l1w_[4]; unsigned l1b_[4];
    #pragma unroll
    for (int k = 0; k < 4; ++k) {
        int e = tid + (k << 8); if (e >= HW) e = 0;
        int rw = e / 28;
        l1w_[k] = rw; l1b_[k] = 1u << (e - rw * 28);
    }
    // conv1 quad (tid < 169): pooled (pi,pj), all 4 channels
    bool okq = tid < 169;
    int qq1 = okq ? tid : 0;
    int pi1 = qq1 / 13, pj1 = qq1 - pi1 * 13;
    int sr1 = 2 * pi1; unsigned sh1 = (unsigned)(2 * pj1);
    unsigned pb1 = 1u << (pj1 + 1);
    // conv2: item A = tid (<264 always ok); item B for tids 248..255 = 256+(tid-248)
    bool hasB = tid >= 248;
    int i2cA, lb2A, p2wA; unsigned js2A, b20A, b21A;
    int i2cB, lb2B, p2wB; unsigned js2B, b20B, b21B;
    {
        int m = tid;
        int row = m / 6, sub = m - row * 6;
        int j0 = (sub < 5) ? 2 * sub : 10;
        int c = row / 11, i2 = row - c * 11;
        i2cA = i2; js2A = (unsigned)(j0 + 1); lb2A = c * 192;
        p2wA = c * 6 + ((i2 + 1) >> 1);
        b20A = 1u << (j0 >> 1);
        b21A = (sub < 5) ? (2u << (j0 >> 1)) : 0u;
        m = hasB ? 256 + (tid - 248) : 0;
        row = m / 6; sub = m - row * 6;
        j0 = (sub < 5) ? 2 * sub : 10;
        c = row / 11; i2 = row - c * 11;
        i2cB = i2; js2B = (unsigned)(j0 + 1); lb2B = c * 192;
        p2wB = c * 6 + ((i2 + 1) >> 1);
        b20B = 1u << (j0 >> 1);
        b21B = (sub < 5) ? (2u << (j0 >> 1)) : 0u;
    }
    // conv3 (tid < 16)
    int rr3 = (tid >> 2) & 3, cc3 = tid & 3;

    // ---------------- membranes (registers) ----------------
    float v2q[16] = {};
    float v3A[2] = {0.f, 0.f}, v3B[2] = {0.f, 0.f};
    float v1m[4] = {};
    float v4 = 0.f, pred = 0.f;

    const float* lutf = (const float*)lut;
    (void)lutf;

    // ---------------- layer-major chunked loop ----------------
    #pragma unroll 1
    for (int c = 0; c < TSTEPS / TCHUNK; ++c) {
        // ==== P1: layer1 x TCHUNK (all threads) ====
        #pragma unroll 1
        for (int tt = 0; tt < TCHUNK; ++tt) {
            unsigned* s1 = s1m + tt * 28;
            #pragma unroll
            for (int k = 0; k < 4; ++k) {
                if (k < 3 || tid < 16) {
                    float v = fadd(v1m[k], dnr[k]);
                    bool spk = v >= 4.5f;
                    v1m[k] = spk ? 0.f : v;
                    if (spk) atomicOr(&s1[l1w_[k]], l1b_[k]);
                }
            }
        }
        __syncthreads();

        // ==== P2: conv1 x TCHUNK (tid<169) | zero p2m (tid>=169) ====
        if (okq) {
            #pragma unroll 1
            for (int tt = 0; tt < TCHUNK; ++tt) {
                const unsigned* s1 = s1m + tt * 28;
                unsigned m0 = s1[sr1], m1 = s1[sr1 + 1], m2 = s1[sr1 + 2], m3 = s1[sr1 + 3];
                unsigned a = UBFE(m0, sh1, 4), bq = UBFE(m1, sh1, 4),
                         cq = UBFE(m2, sh1, 4), dq = UBFE(m3, sh1, 4);
                unsigned a7 = a & 7u, b7 = bq & 7u, c7 = cq & 7u, d7 = dq & 7u;
                unsigned a1 = a >> 1, b1 = bq >> 1, c1 = cq >> 1, d1 = dq >> 1;
                unsigned p00 = a7 | (b7 << 3) | (c7 << 6);
                unsigned p01 = a1 | (b1 << 3) | (c1 << 6);
                unsigned p10 = b7 | (c7 << 3) | (d7 << 6);
                unsigned p11 = b1 | (c1 << 3) | (d1 << 6);
                float4 e00 = lut[p00], e01 = lut[p01], e10 = lut[p10], e11 = lut[p11];
                unsigned cb0 = 0, cb1 = 0, cb2 = 0, cb3 = 0;
                #define C1U(E, ci) { float v; bool s; \
                    v = fadd(v2q[(ci)*4+0], E.x); s = v>=4.5f; v2q[(ci)*4+0] = s?0.f:v; cb0 |= (unsigned)s; \
                    v = fadd(v2q[(ci)*4+1], E.y); s = v>=4.5f; v2q[(ci)*4+1] = s?0.f:v; cb1 |= (unsigned)s; \
                    v = fadd(v2q[(ci)*4+2], E.z); s = v>=4.5f; v2q[(ci)*4+2] = s?0.f:v; cb2 |= (unsigned)s; \
                    v = fadd(v2q[(ci)*4+3], E.w); s = v>=4.5f; v2q[(ci)*4+3] = s?0.f:v; cb3 |= (unsigned)s; }
                C1U(e00, 0) C1U(e01, 1) C1U(e10, 2) C1U(e11, 3)
                #undef C1U
                unsigned* p1 = p1m + tt * 52;
                if (cb0) atomicOr(&p1[pi1],      pb1);
                if (cb1) atomicOr(&p1[13 + pi1], pb1);
                if (cb2) atomicOr(&p1[26 + pi1], pb1);
                if (cb3) atomicOr(&p1[39 + pi1], pb1);
            }
        } else {
            #pragma unroll
            for (int j = 0; j < 3; ++j) {
                int idx = (tid - 169) + 87 * j;
                if (idx < TCHUNK * 24) p2m[idx] = 0u;
            }
        }
        __syncthreads();

        // ==== P3: conv2 x TCHUNK (item A all; item B wave-3 lanes only) ====
        #pragma unroll 1
        for (int tt = 0; tt < TCHUNK; ++tt) {
            const unsigned* p1 = p1m + tt * 52;
            unsigned* p2 = p2m + tt * 24;
            float accA = 0.f, accB = 0.f;
            #pragma unroll
            for (int ic = 0; ic < 4; ++ic)
                #pragma unroll
                for (int ki = 0; ki < 3; ++ki) {
                    unsigned row = p1[ic * 13 + i2cA + ki];
                    unsigned idx = UBFE(row, js2A, 4);
                    float2 e = lut2[lb2A + (ic * 3 + ki) * 16 + idx];
                    accA = fadd(accA, e.x);
                    accB = fadd(accB, e.y);
                }
            float va = fadd(v3A[0], accA);
            float vb = fadd(v3A[1], accB);
            bool sa = va >= 1.0f, sb = vb >= 1.0f;
            v3A[0] = sa ? 0.f : va; v3A[1] = sb ? 0.f : vb;
            unsigned orm = (sa ? b20A : 0u) | (sb ? b21A : 0u);
            if (orm) atomicOr(&p2[p2wA], orm);
        }
        if (hasB) {
            #pragma unroll 1
            for (int tt = 0; tt < TCHUNK; ++tt) {
                const unsigned* p1 = p1m + tt * 52;
                unsigned* p2 = p2m + tt * 24;
                float accA = 0.f, accB = 0.f;
                #pragma unroll
                for (int ic = 0; ic < 4; ++ic)
                    #pragma unroll
                    for (int ki = 0; ki < 3; ++ki) {
                        unsigned row = p1[ic * 13 + i2cB + ki];
                        unsigned idx = UBFE(row, js2B, 4);
                        float2 e = lut2[lb2B + (ic * 3 + ki) * 16 + idx];
                        accA = fadd(accA, e.x);
                        accB = fadd(accB, e.y);
                    }
                float va = fadd(v3B[0], accA);
                float vb = fadd(v3B[1], accB);
                bool sa = va >= 1.0f, sb = vb >= 1.0f;
                v3B[0] = sa ? 0.f : va; v3B[1] = sb ? 0.f : vb;
                unsigned orm = (sa ? b20B : 0u) | (sb ? b21B : 0u);
                if (orm) atomicOr(&p2[p2wB], orm);
            }
        }
        __syncthreads();

        // ==== P4: conv3+LIF x TCHUNK (tid<16) | zero s1m+p1m (tid>=16) ====
        if (tid < 16) {
            #pragma unroll 1
            for (int tt = 0; tt < TCHUNK; ++tt) {
                const unsigned* p2 = p2m + tt * 24;
                float acc = 0.f;
                #pragma unroll
                for (int ic = 0; ic < 4; ++ic)
                    #pragma unroll
                    for (int ki = 0; ki < 3; ++ki) {
                        unsigned row = p2[ic * 6 + rr3 + ki];
                        unsigned idx = UBFE(row, cc3, 3);
                        acc = fadd(acc, lut3[(ic * 3 + ki) * 8 + idx]);
                    }
                v4 = fadd(v4, fmul(fsub(acc, v4), 0.5f));
                if (v4 >= 1.0f) { pred += 1.f; v4 = 0.f; }
            }
        } else {
            #pragma unroll
            for (int j = 0; j < 4; ++j) {
                int idx = (tid - 16) + 240 * j;
                if (idx < 800) {
                    if (idx < 280) s1m[idx] = 0u;
                    else p1m[idx - 280] = 0u;
                }
            }
        }
        __syncthreads();
    }

    if (tid < 16 && blockIdx.x < (unsigned)nbatch)
        out[(size_t)blockIdx.x * 16 + tid] = __fdiv_rn(pred, 30.0f);
}

extern "C" void kernel_launch(void* const* d_in, const int* in_sizes, int n_in,
                              void* d_out, int out_size, void* d_ws, size_t ws_size,
                              hipStream_t stream) {
    const float* x  = (const float*)d_in[0];
    const float* w1 = (const float*)d_in[1];
    const float* w2 = (const float*)d_in[2];
    const float* w3 = (const float*)d_in[3];
    float* out = (float*)d_out;
    unsigned int* dmax = (unsigned int*)d_ws;
    float* dcache = (float*)((char*)d_ws + 16);

    int nbatch = in_sizes[0] / HW;
    size_t need = 16 + (size_t)nbatch * HW * sizeof(float);
    bool cache = ws_size >= need;
    int g4 = (nbatch + 3) / 4;

    // numpy-f32 Gaussian weights: exact f32 steps + correctly-rounded exp
    GaussW gw;
    {
        float fw[7];
        for (int k = 0; k < 7; ++k) {
            float iv = (float)(k - 3);
            float q = iv / 2.0f;
            float e = -0.5f * (q * q);
            fw[k] = (float)exp((double)e);
        }
        float s = 0.0f;
        for (int k = 0; k < 7; ++k) s += fw[k];
        for (int k = 0; k < 7; ++k) gw.w[k] = fw[k] / s;
    }

    hipLaunchKernelGGL(init_kernel, dim3(1), dim3(1), 0, stream, dmax);
    if (cache) {
        hipLaunchKernelGGL(dmax_kernel<true>, dim3(g4), dim3(256), 0, stream,
                           x, nbatch, gw, dmax, dcache);
        hipLaunchKernelGGL(sim_kernel<true>, dim3(nbatch), dim3(256), 0, stream,
                           x, nbatch, w1, w2, w3, gw, dmax, dcache, out);
    } else {
        hipLaunchKernelGGL(dmax_kernel<false>, dim3(g4), dim3(256), 0, stream,
                           x, nbatch, gw, dmax, dcache);
        hipLaunchKernelGGL(sim_kernel<false>, dim3(nbatch), dim3(256), 0, stream,
                           x, nbatch, w1, w2, w3, gw, dmax, dcache, out);
    }
}